// Round 1
// baseline (404.939 us; speedup 1.0000x reference)
//
#include <hip/hip_runtime.h>

#define N 4096
#define TILE 64
#define HALO 5
#define R (TILE + 2 * HALO)   // 74: tile region incl. halo
#define S (R + 1)             // 75: LDS row stride (odd -> no bank-stride aliasing)
#define NT 256
#define ITERS 5

// Fused 5-iteration dilate->sigmoid->accumulate recurrence.
// Each block owns a 64x64 core; loads 74x74 pred region (halo=5) into LDS,
// runs 5 stencil iterations double-buffered (valid region shrinks 1/side per
// iter), accumulates per-iteration fn sums + gt sum over the core only.
__global__ __launch_bounds__(NT) void wlc_main(
    const float* __restrict__ pred,
    const float* __restrict__ gt,
    float* __restrict__ ws)
{
    __shared__ float bufA[R * S];
    __shared__ float bufB[R * S];
    __shared__ float red[6][NT / 64];

    const int tid = threadIdx.x;
    const int bx0 = (int)blockIdx.x * TILE - HALO;
    const int by0 = (int)blockIdx.y * TILE - HALO;

    // Stage pred region (zero-fill out-of-image -> matches SAME zero padding;
    // gt=0 there keeps those cells 0 across iterations).
    for (int idx = tid; idx < R * R; idx += NT) {
        int r = idx / R;
        int c = idx - r * R;
        int gy = by0 + r, gx = bx0 + c;
        float p = 0.f;
        if (gy >= 0 && gy < N && gx >= 0 && gx < N)
            p = pred[gy * N + gx];
        bufA[r * S + c] = p;
    }
    __syncthreads();

    float s[ITERS];
#pragma unroll
    for (int i = 0; i < ITERS; ++i) s[i] = 0.f;
    float gsum = 0.f;

    float* cur = bufA;
    float* nxt = bufB;

#pragma unroll
    for (int i = 0; i < ITERS; ++i) {
        const int lo = i + 1;        // valid compute region [lo, hi) per axis
        const int hi = R - 1 - i;    // iter 4 -> exactly the 64x64 core [5,69)
        for (int idx = tid; idx < 72 * 72; idx += NT) {
            int r = idx / 72;
            int c = idx - r * 72;
            int y = r + 1, x = c + 1;
            if (y >= lo && y < hi && x >= lo && x < hi) {
                const float* r0 = cur + (y - 1) * S + x;
                const float* r1 = cur + y * S + x;
                const float* r2 = cur + (y + 1) * S + x;
                float d = r0[-1] + r0[0] + r0[1]
                        + r1[-1] + r1[0] + r1[1]
                        + r2[-1] + r2[0] + r2[1];
                d = fminf(fmaxf(d, 0.f), 1.f);
                float p = r1[0];
                int gy = by0 + y, gx = bx0 + x;
                float g = 0.f;
                if (gy >= 0 && gy < N && gx >= 0 && gx < N)
                    g = gt[gy * N + gx];          // L1-resident (22 KB/tile)
                float t = 20.f * (d - p - 0.5f);
                float sh = __builtin_amdgcn_rcpf(1.f + __expf(-t));
                float fn = g * sh;
                nxt[y * S + x] = p + fn;
                bool core = (y >= HALO) && (y < HALO + TILE) &&
                            (x >= HALO) && (x < HALO + TILE);
                if (core) {
                    s[i] += fn;
                    if (i == ITERS - 1) gsum += g;  // every pixel is core of exactly one tile
                }
            }
        }
        __syncthreads();
        float* t2 = cur; cur = nxt; nxt = t2;
    }

    // Block reduction of 6 partials -> 1 atomic per block per counter.
    float vals[6] = {gsum, s[0], s[1], s[2], s[3], s[4]};
    const int lane = tid & 63, wave = tid >> 6;
#pragma unroll
    for (int k = 0; k < 6; ++k) {
        float v = vals[k];
#pragma unroll
        for (int off = 32; off > 0; off >>= 1)
            v += __shfl_down(v, off, 64);
        if (lane == 0) red[k][wave] = v;
    }
    __syncthreads();
    if (tid < 6) {
        float v = 0.f;
#pragma unroll
        for (int w = 0; w < NT / 64; ++w) v += red[tid][w];
        atomicAdd(&ws[tid * 16], v);  // counters 64B apart -> different channels
    }
}

__global__ void wlc_final(const float* __restrict__ ws, float* __restrict__ out)
{
    float gsum = ws[0];
    float total = 0.f;
#pragma unroll
    for (int i = 0; i < ITERS; ++i) {
        float w = (float)((i + 1) * (i + 1));
        total += w * ws[(i + 1) * 16];
    }
    out[0] = total / gsum;
}

extern "C" void kernel_launch(void* const* d_in, const int* in_sizes, int n_in,
                              void* d_out, int out_size, void* d_ws, size_t ws_size,
                              hipStream_t stream)
{
    const float* pred = (const float*)d_in[0];
    const float* gtp  = (const float*)d_in[1];
    float* ws = (float*)d_ws;

    // d_ws is poisoned 0xAA before every launch -> zero the 6 counters each call.
    hipMemsetAsync(d_ws, 0, 6 * 16 * sizeof(float), stream);

    dim3 grid(N / TILE, N / TILE);
    wlc_main<<<grid, NT, 0, stream>>>(pred, gtp, ws);
    wlc_final<<<1, 1, 0, stream>>>(ws, (float*)d_out);
}

// Round 2
// 266.647 us; speedup vs baseline: 1.5186x; 1.5186x over previous
//
#include <hip/hip_runtime.h>

#define N 4096
#define CORE 56
#define HALO 5
#define REG 66            // staged rows/cols = CORE + 2*HALO
#define STR 76            // LDS row stride (floats); %8==4 limits b128 bank aliasing
#define NT 256
#define ITERS 5
#define GRID 74           // ceil(4096/56)

// LDS layout: staged cell (y,x), y,x in [0,66), stored at y*STR + (x+3).
// The +3 shift makes every float4 access (A/B blocks, writes, staging) 16B
// aligned. Compute region is FIXED at staged [1,65)^2 every iteration; the
// never-updated ring (row 0/65, col 0/65) goes stale, contaminating at most
// ring<=4 after 5 iters; sums only read the core (ring>=5) which stays exact.
__global__ __launch_bounds__(NT, 3) void wlc_main(
    const float* __restrict__ pred,
    const float* __restrict__ gt,
    float* __restrict__ ws)
{
    __shared__ float bufA[REG * STR];
    __shared__ float bufB[REG * STR];
    __shared__ float red[6][NT / 64];

    const int tid = threadIdx.x;
    const int bX = blockIdx.x, bY = blockIdx.y;
    const int bx0 = bX * CORE - HALO;
    const int by0 = bY * CORE - HALO;
    const bool interior = (bX >= 1) && (bX <= 72) && (bY >= 1) && (bY <= 72);

    // ---- stage pred region into bufA ----
    if (interior) {
        // 18 aligned float4 per row cover LDS offsets [0,72);
        // global col start bx0-3 = 56*bX-8 is a multiple of 4.
        for (int idx = tid; idx < REG * 18; idx += NT) {
            int r = idx / 18;
            int k = idx - r * 18;
            const float4 v = *(const float4*)(pred + (by0 + r) * N + (bx0 - 3 + 4 * k));
            *(float4*)(bufA + r * STR + 4 * k) = v;
        }
    } else {
        for (int idx = tid; idx < REG * 72; idx += NT) {
            int r = idx / 72;
            int c = idx - r * 72;
            int gy = by0 + r, gx = bx0 + c - 3;
            float v = 0.f;
            if (gy >= 0 && gy < N && gx >= 0 && gx < N) v = pred[gy * N + gx];
            bufA[r * STR + c] = v;
        }
    }

    // ---- per-thread register tile coords + loop-invariant gt (16 cells) ----
    const int tx = tid & 15, ty = tid >> 4;
    const int y0 = 1 + 4 * ty;           // first output row (staged coords)
    const int x0 = 1 + 4 * tx;           // first output col
    float4 g4[4];
    if (interior) {
#pragma unroll
        for (int j = 0; j < 4; ++j)
            g4[j] = *(const float4*)(gt + (by0 + y0 + j) * N + (bx0 + x0));
    } else {
#pragma unroll
        for (int j = 0; j < 4; ++j) {
            int gy = by0 + y0 + j;
            float t0 = 0.f, t1 = 0.f, t2 = 0.f, t3 = 0.f;
            if (gy >= 0 && gy < N) {
                int gx = bx0 + x0;
                if (gx + 0 >= 0 && gx + 0 < N) t0 = gt[gy * N + gx + 0];
                if (gx + 1 >= 0 && gx + 1 < N) t1 = gt[gy * N + gx + 1];
                if (gx + 2 >= 0 && gx + 2 < N) t2 = gt[gy * N + gx + 2];
                if (gx + 3 >= 0 && gx + 3 < N) t3 = gt[gy * N + gx + 3];
            }
            g4[j] = make_float4(t0, t1, t2, t3);
        }
    }

    __syncthreads();

    // ---- copy never-computed ring into bufB (any defined value works;
    //      staleness only reaches ring<=4, core is ring>=5) ----
    for (int k = tid; k < 36; k += NT) {
        int r = (k < 18) ? 0 : (REG - 1);
        int c = (k < 18 ? k : k - 18) * 4;
        *(float4*)(bufB + r * STR + c) = *(const float4*)(bufA + r * STR + c);
    }
    for (int k = tid; k < 128; k += NT) {
        int y = 1 + (k >> 1);
        int off = y * STR + ((k & 1) ? 68 : 3);
        bufB[off] = bufA[off];
    }
    // No extra barrier: ring copy writes bufB ring; iter-0 compute reads bufA
    // and writes disjoint bufB interior; the end-of-iter-0 barrier orders both.

    const bool coremask = (tx >= 1) && (tx <= 14) && (ty >= 1) && (ty <= 14);
    float s[ITERS];
#pragma unroll
    for (int i = 0; i < ITERS; ++i) s[i] = 0.f;
    float gsum = 0.f;
    if (coremask) {
#pragma unroll
        for (int j = 0; j < 4; ++j)
            gsum += g4[j].x + g4[j].y + g4[j].z + g4[j].w;
    }

    const float C1 = 28.853900817779268f;  // 20*log2(e)
    const float C2 = 14.426950408889634f;  // C1*0.5

    float* cur = bufA;
    float* nxt = bufB;
    const int cbase = 4 * tx;              // LDS col offset of A block

#pragma unroll
    for (int i = 0; i < ITERS; ++i) {
        float4 rs[6], pb[6];
#pragma unroll
        for (int r = 0; r < 6; ++r) {
            const float* row = cur + (y0 - 1 + r) * STR + cbase;
            float4 A = *(const float4*)(row);        // staged x0-4..x0-1
            float4 B = *(const float4*)(row + 4);    // staged x0..x0+3
            float  C = row[8];                       // staged x0+4
            pb[r] = B;
            rs[r].x = A.w + B.x + B.y;
            rs[r].y = B.x + B.y + B.z;
            rs[r].z = B.y + B.z + B.w;
            rs[r].w = B.z + B.w + C;
        }
        float fnsum = 0.f;
#pragma unroll
        for (int j = 0; j < 4; ++j) {
            float4 d, p = pb[j + 1], o;
            d.x = rs[j].x + rs[j + 1].x + rs[j + 2].x;
            d.y = rs[j].y + rs[j + 1].y + rs[j + 2].y;
            d.z = rs[j].z + rs[j + 1].z + rs[j + 2].z;
            d.w = rs[j].w + rs[j + 1].w + rs[j + 2].w;
#define WLC_COMP(cc)                                                     \
            {                                                            \
                float dd = fminf(fmaxf(d.cc, 0.f), 1.f);                 \
                float u  = __builtin_fmaf(p.cc - dd, C1, C2);            \
                float e  = __builtin_amdgcn_exp2f(u);                    \
                float sh = __builtin_amdgcn_rcpf(1.f + e);               \
                float fnc = g4[j].cc * sh;                               \
                o.cc = p.cc + fnc;                                       \
                fnsum += fnc;                                            \
            }
            WLC_COMP(x) WLC_COMP(y) WLC_COMP(z) WLC_COMP(w)
#undef WLC_COMP
            *(float4*)(nxt + (y0 + j) * STR + cbase + 4) = o;
        }
        if (coremask) s[i] += fnsum;
        __syncthreads();
        float* t = cur; cur = nxt; nxt = t;
    }

    // ---- block reduction: 6 partials -> 1 atomic each ----
    float vals[6] = {gsum, s[0], s[1], s[2], s[3], s[4]};
    const int lane = tid & 63, wave = tid >> 6;
#pragma unroll
    for (int k = 0; k < 6; ++k) {
        float v = vals[k];
#pragma unroll
        for (int off = 32; off > 0; off >>= 1)
            v += __shfl_down(v, off, 64);
        if (lane == 0) red[k][wave] = v;
    }
    __syncthreads();
    if (tid < 6) {
        float v = 0.f;
#pragma unroll
        for (int w = 0; w < NT / 64; ++w) v += red[tid][w];
        atomicAdd(&ws[tid * 16], v);
    }
}

__global__ void wlc_final(const float* __restrict__ ws, float* __restrict__ out)
{
    float gsum = ws[0];
    float total = 0.f;
#pragma unroll
    for (int i = 0; i < ITERS; ++i) {
        float w = (float)((i + 1) * (i + 1));
        total += w * ws[(i + 1) * 16];
    }
    out[0] = total / gsum;
}

extern "C" void kernel_launch(void* const* d_in, const int* in_sizes, int n_in,
                              void* d_out, int out_size, void* d_ws, size_t ws_size,
                              hipStream_t stream)
{
    const float* pred = (const float*)d_in[0];
    const float* gtp  = (const float*)d_in[1];
    float* ws = (float*)d_ws;

    hipMemsetAsync(d_ws, 0, 6 * 16 * sizeof(float), stream);

    dim3 grid(GRID, GRID);
    wlc_main<<<grid, NT, 0, stream>>>(pred, gtp, ws);
    wlc_final<<<1, 1, 0, stream>>>(ws, (float*)d_out);
}